// Round 8
// baseline (1497.323 us; speedup 1.0000x reference)
//
#include <hip/hip_runtime.h>
#include <hip/hip_bf16.h>

// DeepLSTM on MI355X — v8: producer/consumer WAVE SPECIALIZATION.
//
// v7 post-mortem: 8 lockstep waves used the pipes serially (sum of pipe
// budgets == measured period; ~no overlap). v8: 1024 threads, 16 waves,
// 4/SIMD. R-gang (waves 0-7): recurrent h@W_hh + activation only, one
// barrier per step. X-gang (waves 8-15): x@W_ih one window ahead into a
// 64KB f32 LDS gx buffer (slot recycled with one-window lag), ring stores,
// polls/publishes, L0 embed gather, L7 out-projection — all overlapped with
// R's compute. X reads A-fragments straight from ring/embed (no LDS staging).
// Weights split: whh in R regs, wih in X regs -> both paths < 128 VGPR.
// Both paths execute exactly 514 barriers (counts must match).
//
// Window schedule (chunk ch = steps 2ch, 2ch+1):
//  W0(ch): R step 2ch | X: ring-store(2ch-1); phase1(step 2ch+1 -> gx[1])
//  W1(ch): R step 2ch+1 | X: publish flag=2ch; phase1(step 2ch+2 -> gx[0]);
//          ring-store(2ch) [L7: out-proj instead of ring work]
//  epilogue: ring-store(511), barrier, publish 512 [L7: out-proj(511)]
//
// ws: [0,8KB) flags (prod@0, cons@4KB, 128B stride); [8KB,...) ring
//     [pair][RING_T][16][128] bf16, full history when ws >= 57 MB.

#define T_ 512
#define L_ 8
#define H_ 128
#define G4_ 512
#define OUT_ 65
#define B_ 64
#define NG_ 4
#define BG_ 16
#define LDSW_ 136                          // padded LDS row stride (bf16)
#define HT_OFF_ (B_ * T_ * OUT_)           // 2129920
#define CT_OFF_ (HT_OFF_ + L_ * B_ * H_)   // 2195456
#define STEP_U64_ 512                      // one step's h-tile: 16x128 bf16 = 4KB
#define NCH_ (T_ / 2)

typedef __bf16 bf16_t;
typedef bf16_t bf16x8 __attribute__((ext_vector_type(8)));
typedef float f32x4 __attribute__((ext_vector_type(4)));
typedef unsigned long long u64;

union U128 { uint4 u; bf16x8 b; };

__device__ __forceinline__ float rcpf(float x) { return __builtin_amdgcn_rcpf(x); }
__device__ __forceinline__ float sigm(float x) { return rcpf(1.f + __expf(-x)); }
__device__ __forceinline__ float tanh_fast(float x) {
  const float e = __expf(-2.f * fabsf(x));
  const float r = 2.f * rcpf(1.f + e) - 1.f;
  return copysignf(r, x);
}
__device__ __forceinline__ int flag_ld(int* p) {
  return __hip_atomic_load(p, __ATOMIC_RELAXED, __HIP_MEMORY_SCOPE_AGENT);
}
__device__ __forceinline__ void flag_st(int* p, int v) {
  __hip_atomic_store(p, v, __ATOMIC_RELAXED, __HIP_MEMORY_SCOPE_AGENT);
}

__global__ void zero_flags(int* flags) { flags[blockIdx.x * 1024 + threadIdx.x] = 0; }

template <int RING_T>
__global__ __launch_bounds__(1024, 4)
void lstm_pipe(const int* __restrict__ xids, const float* __restrict__ embed,
               const float* __restrict__ wih_g, const float* __restrict__ bih_g,
               const float* __restrict__ whh_g, const float* __restrict__ bhh_g,
               const float* __restrict__ wout_g, const float* __restrict__ bout_g,
               float* __restrict__ out, int* __restrict__ flags,
               u64* __restrict__ ring) {
  const int l    = blockIdx.x >> 2;
  const int g    = blockIdx.x & 3;
  const int tid  = threadIdx.x;
  const bool isX = tid >= 512;
  const int lane = tid & 63;
  const int wv   = (tid >> 6) & 7;   // gang-local wave id 0..7
  const int q    = lane >> 4;
  const int col  = lane & 15;
  const int xtid = tid & 511;        // gang-local thread id

  __shared__ f32x4 gx_lds[2][4][8][64];              // 64 KB: [slot][c][wv][lane]
  __shared__ __align__(16) bf16_t hist[2][16 * LDSW_];  // h double-buffer by step parity
  __shared__ uint4 wout_lds[5][4][64];               // 20 KB: L7 out-proj weights

  int* myprod   = flags + ((l * NG_ + g) << 5);
  int* prevprod = (l > 0) ? flags + (((l - 1) * NG_ + g) << 5) : flags;
  int* mycons   = flags + 1024 + ((l * NG_ + g) << 5);
  int* nextcons = (l < L_ - 1) ? flags + 1024 + (((l + 1) * NG_ + g) << 5) : flags;
  u64* myring  = (l < L_ - 1) ? ring + (size_t)(l * NG_ + g) * RING_T * STEP_U64_ : ring;
  const u64* srcring = (l > 0) ? ring + (size_t)((l - 1) * NG_ + g) * RING_T * STEP_U64_ : ring;

  // zero hist (both gangs participate)
  for (int i = tid; i < 2 * 16 * LDSW_; i += 1024) ((bf16_t*)hist)[i] = (bf16_t)(0.f);

  if (!isX) {
    // ================= R-GANG: recurrent steps only =================
    bf16x8 whh[4][4];
#pragma unroll
    for (int c = 0; c < 4; ++c) {
      const int n = wv * 16 + c * 128 + col;
#pragma unroll
      for (int kt = 0; kt < 4; ++kt) {
        bf16x8 b;
#pragma unroll
        for (int jj = 0; jj < 8; ++jj)
          b[jj] = (bf16_t)whh_g[(l * H_ + (kt * 32 + q * 8 + jj)) * G4_ + n];
        whh[c][kt] = b;
      }
    }
    float cst[4] = {0.f, 0.f, 0.f, 0.f};
    const int aoff = col * LDSW_ + q * 8;
    const int jc   = wv * 16 + col;

    __syncthreads();  // prologue barrier (X staged gx[0])

#pragma unroll 1
    for (int s = 0; s < T_; ++s) {
      f32x4 acc[4];
#pragma unroll
      for (int c = 0; c < 4; ++c) acc[c] = gx_lds[s & 1][c][wv][lane];
      bf16x8 ha[4];
#pragma unroll
      for (int kt = 0; kt < 4; ++kt)
        ha[kt] = *(const bf16x8*)(&hist[(s + 1) & 1][aoff + kt * 32]);
#pragma unroll
      for (int c = 0; c < 4; ++c)
#pragma unroll
        for (int kt = 0; kt < 4; ++kt)
          acc[c] = __builtin_amdgcn_mfma_f32_16x16x32_bf16(ha[kt], whh[c][kt], acc[c], 0, 0, 0);

      float hv[4];
      bf16_t hb[4];
#pragma unroll
      for (int r = 0; r < 4; ++r) {
        const float iv = sigm(acc[0][r]);
        const float fv = sigm(acc[1][r]);
        const float gv = tanh_fast(acc[2][r]);
        const float ov = sigm(acc[3][r]);
        const float cv = fv * cst[r] + iv * gv;
        cst[r] = cv;
        const float h = ov * tanh_fast(cv);
        hv[r] = h;
        hb[r] = (bf16_t)h;
      }
#pragma unroll
      for (int r = 0; r < 4; ++r)
        hist[s & 1][(q * 4 + r) * LDSW_ + jc] = hb[r];
      if (s == T_ - 1) {
#pragma unroll
        for (int r = 0; r < 4; ++r) {
          const int b = g * BG_ + q * 4 + r;
          out[HT_OFF_ + (l * B_ + b) * H_ + jc] = hv[r];
          out[CT_OFF_ + (l * B_ + b) * H_ + jc] = cst[r];
        }
      }
      __syncthreads();  // end of window s
    }
    __syncthreads();  // epilogue barrier
  } else {
    // ================= X-GANG: everything else =================
    bf16x8 wih[4][4];
    float bias[4];
#pragma unroll
    for (int c = 0; c < 4; ++c) {
      const int n = wv * 16 + c * 128 + col;
#pragma unroll
      for (int kt = 0; kt < 4; ++kt) {
        bf16x8 a;
#pragma unroll
        for (int jj = 0; jj < 8; ++jj)
          a[jj] = (bf16_t)wih_g[(l * H_ + (kt * 32 + q * 8 + jj)) * G4_ + n];
        wih[c][kt] = a;
      }
      bias[c] = bih_g[l * G4_ + n] + bhh_g[l * G4_ + n];
    }
    float bo = 0.f;
    if (l == L_ - 1 && wv < 5) {
      const int n = wv * 16 + col;
#pragma unroll
      for (int kt = 0; kt < 4; ++kt) {
        U128 w;
#pragma unroll
        for (int jj = 0; jj < 8; ++jj) {
          const int k = kt * 32 + q * 8 + jj;
          w.b[jj] = (n < OUT_) ? (bf16_t)wout_g[k * OUT_ + n] : (bf16_t)(0.f);
        }
        wout_lds[wv][kt][lane] = w.u;
      }
      if (n < OUT_) bo = bout_g[n];
    }

    int seen_prod = 0, seen_cons = 0;

    auto x_phase1 = [&](int step, int slot) {
      bf16x8 xa[4];
      if (l == 0) {
        const int token = xids[(g * BG_ + col) * T_ + step];
        const float* erow = embed + token * H_;
#pragma unroll
        for (int kt = 0; kt < 4; ++kt) {
          const float4 e0 = *(const float4*)(erow + kt * 32 + q * 8);
          const float4 e1 = *(const float4*)(erow + kt * 32 + q * 8 + 4);
          bf16x8 v;
          v[0] = (bf16_t)e0.x; v[1] = (bf16_t)e0.y; v[2] = (bf16_t)e0.z; v[3] = (bf16_t)e0.w;
          v[4] = (bf16_t)e1.x; v[5] = (bf16_t)e1.y; v[6] = (bf16_t)e1.z; v[7] = (bf16_t)e1.w;
          xa[kt] = v;
        }
      } else {
        const int need = step + 1;
        if (seen_prod < need) {
          int v;
          do { v = flag_ld(prevprod); } while (v < need);
          seen_prod = v;
        }
        __builtin_amdgcn_fence(__ATOMIC_ACQUIRE, "agent");  // kill stale/prefetched lines
        const uint4* base = (const uint4*)(srcring + (size_t)(step & (RING_T - 1)) * STEP_U64_);
#pragma unroll
        for (int kt = 0; kt < 4; ++kt) {
          U128 t;
          t.u = base[col * 16 + kt * 4 + q];
          xa[kt] = t.b;
        }
      }
#pragma unroll
      for (int c = 0; c < 4; ++c) {
        f32x4 a = (f32x4){bias[c], bias[c], bias[c], bias[c]};
#pragma unroll
        for (int kt = 0; kt < 4; ++kt)
          a = __builtin_amdgcn_mfma_f32_16x16x32_bf16(xa[kt], wih[c][kt], a, 0, 0, 0);
        gx_lds[slot][c][wv][lane] = a;
      }
    };

    auto x_ring_store = [&](int step) {  // fire-and-forget; drained at next barrier
      if (RING_T < T_ && step >= RING_T) {
        const int need = step - RING_T + 1;
        if (seen_cons < need) {
          int v;
          do { v = flag_ld(nextcons); } while (v < need);
          seen_cons = v;
        }
      }
      const u64 val = *(const u64*)(&hist[step & 1][(xtid >> 5) * LDSW_ + ((xtid & 31) << 2)]);
      myring[(size_t)(step & (RING_T - 1)) * STEP_U64_ + xtid] = val;
    };

    auto x_outproj = [&](int step) {  // L7, waves 0..4
      if (wv < 5) {
        f32x4 oacc = (f32x4){0.f, 0.f, 0.f, 0.f};
#pragma unroll
        for (int kt = 0; kt < 4; ++kt) {
          U128 w;
          w.u = wout_lds[wv][kt][lane];
          const bf16x8 a = *(const bf16x8*)(&hist[step & 1][col * LDSW_ + kt * 32 + q * 8]);
          oacc = __builtin_amdgcn_mfma_f32_16x16x32_bf16(a, w.b, oacc, 0, 0, 0);
        }
        const int n = wv * 16 + col;
        if (n < OUT_) {
#pragma unroll
          for (int r = 0; r < 4; ++r) {
            const int b = g * BG_ + q * 4 + r;
            out[(b * T_ + step) * OUT_ + n] = oacc[r] + bo;
          }
        }
      }
    };

    // prologue: gx[0] for step 0
    x_phase1(0, 0);
    __syncthreads();  // prologue barrier

#pragma unroll 1
    for (int ch = 0; ch < NCH_; ++ch) {
      // ---- W0: R runs step 2ch ----
      if (l < L_ - 1) {
        if (ch > 0) x_ring_store(2 * ch - 1);
      } else {
        if (ch > 0) x_outproj(2 * ch - 1);
      }
      x_phase1(2 * ch + 1, 1);
      __syncthreads();

      // ---- W1: R runs step 2ch+1 ----
      if (l < L_ - 1 && ch > 0 && xtid == 0) {
        __builtin_amdgcn_fence(__ATOMIC_RELEASE, "agent");  // flush ring stores (<= step 2ch-1)
        flag_st(myprod, 2 * ch);
      }
      if (RING_T < T_ && l > 0 && xtid == 0) flag_st(mycons, 2 * ch + 2);
      if (ch + 1 < NCH_) x_phase1(2 * ch + 2, 0);
      if (l < L_ - 1) x_ring_store(2 * ch);
      else x_outproj(2 * ch);
      __syncthreads();
    }

    // epilogue
    if (l < L_ - 1) x_ring_store(T_ - 1);
    else x_outproj(T_ - 1);
    __syncthreads();  // drains ring stores of step 511 (per-wave vmcnt before barrier)
    if (l < L_ - 1 && xtid == 0) {
      __builtin_amdgcn_fence(__ATOMIC_RELEASE, "agent");
      flag_st(myprod, T_);
    }
  }
}

extern "C" void kernel_launch(void* const* d_in, const int* in_sizes, int n_in,
                              void* d_out, int out_size, void* d_ws, size_t ws_size,
                              hipStream_t stream) {
  (void)in_sizes; (void)n_in; (void)out_size;
  const int*   x     = (const int*)d_in[0];
  const float* embed = (const float*)d_in[1];
  const float* w_ih  = (const float*)d_in[2];
  const float* b_ih  = (const float*)d_in[3];
  const float* w_hh  = (const float*)d_in[4];
  const float* b_hh  = (const float*)d_in[5];
  const float* w_out = (const float*)d_in[6];
  const float* b_out = (const float*)d_in[7];
  float* out = (float*)d_out;

  int* flags = (int*)d_ws;                     // 8 KB: prod@0, cons@4KB
  u64* ring  = (u64*)((char*)d_ws + 8192);

  hipLaunchKernelGGL(zero_flags, dim3(2), dim3(1024), 0, stream, flags);

  auto need = [&](int ring_t) { return (size_t)8192 + (size_t)28 * ring_t * 4096; };

  if (ws_size >= need(512)) {        // 57 MB: full history, no back-pressure
    hipLaunchKernelGGL((lstm_pipe<512>), dim3(L_ * NG_), dim3(1024), 0, stream,
                       x, embed, w_ih, b_ih, w_hh, b_hh, w_out, b_out, out, flags, ring);
  } else if (ws_size >= need(64)) {  // 7.2 MB
    hipLaunchKernelGGL((lstm_pipe<64>), dim3(L_ * NG_), dim3(1024), 0, stream,
                       x, embed, w_ih, b_ih, w_hh, b_hh, w_out, b_out, out, flags, ring);
  } else {                           // 1.8 MB minimum
    hipLaunchKernelGGL((lstm_pipe<16>), dim3(L_ * NG_), dim3(1024), 0, stream,
                       x, embed, w_ih, b_ih, w_hh, b_hh, w_out, b_out, out, flags, ring);
  }
}

// Round 10
// 1028.961 us; speedup vs baseline: 1.4552x; 1.4552x over previous
//
#include <hip/hip_runtime.h>
#include <hip/hip_bf16.h>

// DeepLSTM on MI355X — v10: v9 with the asm-pin fixed (32-bit components).
//
// v9 failed to compile: gfx950 backend rejects tied "+v" on 128-bit
// aggregates ("tied indirect register inputs"). v10 pins each 32-bit
// component of the weight fragments instead — supported form. Otherwise
// byte-identical to v9 (= v7 skeleton + pinned wih/whh, wout in LDS).
//
// Theory under test (from v8 post-mortem): VGPR_Count=128 in v7 means the
// 128-VGPR weight fragments were NOT register-resident; the compiler
// rematerializes them (8 scalar f32 loads + cvt + pack per fragment) from
// XCD-L2 on every use, putting an L2-latency chain under every step's
// MFMAs. Pinning forces true residency (~208 VGPR, fits 256 @ 2 waves/SIMD).
//
// Grid: 32 blocks x 512 threads; block (l,g) = layer l, batch group g (16 rows).
// ws: [0,8KB) flags (prod@0, cons@4KB, 128B stride); [8KB,...) ring
//     [pair][RING_T][16][128] bf16.

#define T_ 512
#define L_ 8
#define H_ 128
#define G4_ 512
#define OUT_ 65
#define B_ 64
#define NG_ 4
#define BG_ 16
#define LDSW_ 136                          // padded LDS row stride (bf16)
#define HT_OFF_ (B_ * T_ * OUT_)           // 2129920
#define CT_OFF_ (HT_OFF_ + L_ * B_ * H_)   // 2195456
#define STEP_U64_ 512                      // one step's h-tile: 16x128 bf16 = 4KB

typedef __bf16 bf16_t;
typedef bf16_t bf16x8 __attribute__((ext_vector_type(8)));
typedef bf16_t bf16x4 __attribute__((ext_vector_type(4)));
typedef float f32x4 __attribute__((ext_vector_type(4)));
typedef unsigned long long u64;

union U128 { uint4 u; bf16x8 b; };

__device__ __forceinline__ float rcpf(float x) { return __builtin_amdgcn_rcpf(x); }
__device__ __forceinline__ float sigm(float x) { return rcpf(1.f + __expf(-x)); }
__device__ __forceinline__ float tanh_fast(float x) {
  const float e = __expf(-2.f * fabsf(x));
  const float r = 2.f * rcpf(1.f + e) - 1.f;
  return copysignf(r, x);
}
__device__ __forceinline__ int flag_ld(int* p) {
  return __hip_atomic_load(p, __ATOMIC_RELAXED, __HIP_MEMORY_SCOPE_AGENT);
}
__device__ __forceinline__ void flag_st(int* p, int v) {
  __hip_atomic_store(p, v, __ATOMIC_RELAXED, __HIP_MEMORY_SCOPE_AGENT);
}

__global__ void zero_flags(int* flags) { flags[blockIdx.x * 1024 + threadIdx.x] = 0; }

template <int CT, int RING_T>
__global__ __launch_bounds__(512, 2)
void lstm_pipe(const int* __restrict__ xids, const float* __restrict__ embed,
               const float* __restrict__ wih_g, const float* __restrict__ bih_g,
               const float* __restrict__ whh_g, const float* __restrict__ bhh_g,
               const float* __restrict__ wout_g, const float* __restrict__ bout_g,
               float* __restrict__ out, int* __restrict__ flags,
               u64* __restrict__ ring) {
  static_assert(RING_T >= 2 * CT || RING_T >= T_, "need >=2 chunks of ring slack");
  constexpr int NCH = T_ / CT;
  const int l    = blockIdx.x >> 2;
  const int g    = blockIdx.x & 3;
  const int tid  = threadIdx.x;
  const int wv   = tid >> 6;      // wave 0..7: gate col-tiles {wv, wv+8, wv+16, wv+24}
  const int lane = tid & 63;
  const int q    = lane >> 4;     // quad 0..3
  const int col  = lane & 15;

  __shared__ __align__(16) bf16_t xchunk[CT][16 * LDSW_];  // chunk input, A-layout
  __shared__ __align__(16) bf16_t hist[CT][16 * LDSW_];    // circular h history
  __shared__ uint4 wout_lds[5][4][64];                     // L7 out-proj weights (20 KB)

  // ---- resident weight fragments (bf16, B-layout: lane holds B[k][n], n=col) ----
  U128 wih[4][4], whh[4][4];  // [gate-class c][k-tile kt]
#pragma unroll
  for (int c = 0; c < 4; ++c) {
    const int n = wv * 16 + c * 128 + col;
#pragma unroll
    for (int kt = 0; kt < 4; ++kt) {
      U128 a, b;
#pragma unroll
      for (int jj = 0; jj < 8; ++jj) {
        const int k = kt * 32 + q * 8 + jj;
        a.b[jj] = (bf16_t)wih_g[(l * H_ + k) * G4_ + n];
        b.b[jj] = (bf16_t)whh_g[(l * H_ + k) * G4_ + n];
      }
      wih[c][kt] = a;
      whh[c][kt] = b;
    }
  }
  // PIN the fragments: opaque to remat. 32-bit tied operands (128-bit
  // aggregates are unsupported: "tied indirect register inputs").
#pragma unroll
  for (int c = 0; c < 4; ++c)
#pragma unroll
    for (int kt = 0; kt < 4; ++kt) {
      asm volatile("" : "+v"(wih[c][kt].u.x), "+v"(wih[c][kt].u.y),
                        "+v"(wih[c][kt].u.z), "+v"(wih[c][kt].u.w));
      asm volatile("" : "+v"(whh[c][kt].u.x), "+v"(whh[c][kt].u.y),
                        "+v"(whh[c][kt].u.z), "+v"(whh[c][kt].u.w));
    }

  float bias[4];
#pragma unroll
  for (int c = 0; c < 4; ++c) {
    const int n = wv * 16 + c * 128 + col;
    bias[c] = bih_g[l * G4_ + n] + bhh_g[l * G4_ + n];
  }
  float bo = 0.f;
  const bool has_out = (l == L_ - 1) && (wv < 5);
  if (has_out) {
    const int n = wv * 16 + col;
#pragma unroll
    for (int kt = 0; kt < 4; ++kt) {
      U128 w;
#pragma unroll
      for (int jj = 0; jj < 8; ++jj) {
        const int k = kt * 32 + q * 8 + jj;
        w.b[jj] = (n < OUT_) ? (bf16_t)wout_g[k * OUT_ + n] : (bf16_t)(0.f);
      }
      wout_lds[wv][kt][lane] = w.u;  // stash in LDS, not registers
    }
    if (n < OUT_) bo = bout_g[n];
  }

  int* myprod   = flags + ((l * NG_ + g) << 5);
  int* prevprod = (l > 0) ? flags + (((l - 1) * NG_ + g) << 5) : flags;
  int* mycons   = flags + 1024 + ((l * NG_ + g) << 5);
  int* nextcons = (l < L_ - 1) ? flags + 1024 + (((l + 1) * NG_ + g) << 5) : flags;
  u64* myring  = (l < L_ - 1) ? ring + (size_t)(l * NG_ + g) * RING_T * STEP_U64_ : ring;
  const u64* srcring = (l > 0) ? ring + (size_t)((l - 1) * NG_ + g) * RING_T * STEP_U64_ : ring;

  const int aoff = col * LDSW_ + q * 8;  // A-fragment: m=lane&15, k=q*8+j
  float cst[4] = {0.f, 0.f, 0.f, 0.f};  // c-state: rows m=q*4+r, col j=16*wv+col
  int seen_prod = 0, seen_cons = 0;

  // ---- prologue: zero h_{-1} (hist[CT-1]); acquire chunk 0 ----
  for (int i = tid; i < 16 * LDSW_; i += 512) hist[CT - 1][i] = (bf16_t)(0.f);
  if (l == 0) {
    const int m  = tid >> 5;
    const int c4 = (tid & 31) << 2;
#pragma unroll
    for (int tl = 0; tl < CT; ++tl) {
      const int token = xids[(g * BG_ + m) * T_ + tl];
      const float4 e = *(const float4*)(embed + token * H_ + c4);
      bf16x4 v;
      v[0] = (bf16_t)e.x; v[1] = (bf16_t)e.y; v[2] = (bf16_t)e.z; v[3] = (bf16_t)e.w;
      *(bf16x4*)(&xchunk[tl][m * LDSW_ + c4]) = v;
    }
  } else {
    if (tid == 0) {
      int v;
      do { v = flag_ld(prevprod); } while (v < CT);
      seen_prod = v;
    }
    __syncthreads();
    __builtin_amdgcn_fence(__ATOMIC_ACQUIRE, "agent");
    const int idx = tid >> 2;
    if (idx < CT * 16) {
      const int tl = idx >> 4, m = idx & 15, seg = tid & 3;
      const u64* src = srcring + (size_t)(tl & (RING_T - 1)) * STEP_U64_ + m * 32 + seg * 8;
      bf16_t* dst = &xchunk[tl][m * LDSW_ + seg * 32];
#pragma unroll
      for (int j = 0; j < 4; ++j) *(uint4*)(dst + j * 8) = *(const uint4*)(src + j * 2);
    }
  }
  __syncthreads();  // hist[CT-1] zeroed + xchunk(0) ready + wout_lds ready

#pragma unroll 1
  for (int ch = 0; ch < NCH; ++ch) {
    const int t0 = ch * CT;

    // ===== phase 1: dense x-half, gx[tl][c] = bias[c] + x_tl @ W_ih =====
    f32x4 gx[CT][4];
#pragma unroll
    for (int tl = 0; tl < CT; ++tl) {
      bf16x8 xa[4];
#pragma unroll
      for (int kt = 0; kt < 4; ++kt)
        xa[kt] = *(const bf16x8*)(&xchunk[tl][aoff + kt * 32]);
#pragma unroll
      for (int c = 0; c < 4; ++c) {
        f32x4 a = (f32x4){bias[c], bias[c], bias[c], bias[c]};
#pragma unroll
        for (int kt = 0; kt < 4; ++kt)
          a = __builtin_amdgcn_mfma_f32_16x16x32_bf16(xa[kt], wih[c][kt].b, a, 0, 0, 0);
        gx[tl][c] = a;
      }
    }

    // ===== phase 2: CT recurrent steps (1 barrier each), per-step ring store =====
#pragma unroll
    for (int tl = 0; tl < CT; ++tl) {
      bf16x8 ha[4];
#pragma unroll
      for (int kt = 0; kt < 4; ++kt)
        ha[kt] = *(const bf16x8*)(&hist[(tl + CT - 1) % CT][aoff + kt * 32]);
#pragma unroll
      for (int c = 0; c < 4; ++c)
#pragma unroll
        for (int kt = 0; kt < 4; ++kt)
          gx[tl][c] = __builtin_amdgcn_mfma_f32_16x16x32_bf16(ha[kt], whh[c][kt].b, gx[tl][c], 0, 0, 0);

      float hv[4];
      bf16_t hb[4];
#pragma unroll
      for (int r = 0; r < 4; ++r) {
        const float iv = sigm(gx[tl][0][r]);
        const float fv = sigm(gx[tl][1][r]);
        const float gv = tanh_fast(gx[tl][2][r]);
        const float ov = sigm(gx[tl][3][r]);
        const float cv = fv * cst[r] + iv * gv;
        cst[r] = cv;
        const float h = ov * tanh_fast(cv);
        hv[r] = h;
        hb[r] = (bf16_t)h;
      }
      {
        const int jc = wv * 16 + col;
#pragma unroll
        for (int r = 0; r < 4; ++r)
          hist[tl][(q * 4 + r) * LDSW_ + jc] = hb[r];
      }
      if (t0 + tl == T_ - 1) {  // final hT / cT
        const int jc = wv * 16 + col;
#pragma unroll
        for (int r = 0; r < 4; ++r) {
          const int b = g * BG_ + q * 4 + r;
          out[HT_OFF_ + (l * B_ + b) * H_ + jc] = hv[r];
          out[CT_OFF_ + (l * B_ + b) * H_ + jc] = cst[r];
        }
      }
      __syncthreads();  // hist[tl] published block-wide

      if (l < L_ - 1) {  // fire-and-forget; drained at the boundary barrier
        const u64 val = *(const u64*)(&hist[tl][(tid >> 5) * LDSW_ + ((tid & 31) << 2)]);
        myring[(size_t)((t0 + tl) & (RING_T - 1)) * STEP_U64_ + tid] = val;
      }
    }

    // ===== L7: batched out-projection from hist =====
    if (has_out) {
      const int n = wv * 16 + col;
#pragma unroll
      for (int tl = 0; tl < CT; ++tl) {
        f32x4 oacc = (f32x4){0.f, 0.f, 0.f, 0.f};
#pragma unroll
        for (int kt = 0; kt < 4; ++kt) {
          U128 w;
          w.u = wout_lds[wv][kt][lane];
          const bf16x8 a = *(const bf16x8*)(&hist[tl][col * LDSW_ + kt * 32 + q * 8]);
          oacc = __builtin_amdgcn_mfma_f32_16x16x32_bf16(a, w.b, oacc, 0, 0, 0);
        }
        if (n < OUT_) {
#pragma unroll
          for (int r = 0; r < 4; ++r) {
            const int b = g * BG_ + q * 4 + r;
            out[(b * T_ + (t0 + tl)) * OUT_ + n] = oacc[r] + bo;
          }
        }
      }
    }

    // ===== boundary: drain + publish + acquire(ch+1) =====
    if (ch + 1 < NCH) {
      if (tid == 0) {
        if (RING_T < T_ && l > 0) flag_st(mycons, t0 + CT);  // BEFORE polls (no deadlock)
        if (l > 0) {
          const int target = t0 + 2 * CT;
          if (seen_prod < target) {
            int v;
            do { v = flag_ld(prevprod); } while (v < target);
            seen_prod = v;
          }
        }
        if (RING_T < T_ && l < L_ - 1 && t0 + 2 * CT > RING_T) {
          const int need = t0 + 2 * CT - RING_T;
          if (seen_cons < need) {
            int v;
            do { v = flag_ld(nextcons); } while (v < need);
            seen_cons = v;
          }
        }
      }
      __syncthreads();  // drains all chunk-ch ring stores; gates polls
      if (l < L_ - 1 && tid == 0) {
        __builtin_amdgcn_fence(__ATOMIC_RELEASE, "agent");
        flag_st(myprod, t0 + CT);
      }
      if (l == 0) {
        const int m  = tid >> 5;
        const int c4 = (tid & 31) << 2;
#pragma unroll
        for (int tl = 0; tl < CT; ++tl) {
          const int token = xids[(g * BG_ + m) * T_ + t0 + CT + tl];
          const float4 e = *(const float4*)(embed + token * H_ + c4);
          bf16x4 v;
          v[0] = (bf16_t)e.x; v[1] = (bf16_t)e.y; v[2] = (bf16_t)e.z; v[3] = (bf16_t)e.w;
          *(bf16x4*)(&xchunk[tl][m * LDSW_ + c4]) = v;
        }
      } else {
        __builtin_amdgcn_fence(__ATOMIC_ACQUIRE, "agent");
        const int idx = tid >> 2;
        if (idx < CT * 16) {
          const int tl = idx >> 4, m = idx & 15, seg = tid & 3;
          const u64* src = srcring + (size_t)((t0 + CT + tl) & (RING_T - 1)) * STEP_U64_ + m * 32 + seg * 8;
          bf16_t* dst = &xchunk[tl][m * LDSW_ + seg * 32];
#pragma unroll
          for (int j = 0; j < 4; ++j) *(uint4*)(dst + j * 8) = *(const uint4*)(src + j * 2);
        }
      }
      __syncthreads();  // xchunk(ch+1) ready
    } else if (l < L_ - 1) {
      __syncthreads();  // drain last chunk's ring stores
      if (tid == 0) {
        __builtin_amdgcn_fence(__ATOMIC_RELEASE, "agent");
        flag_st(myprod, T_);
      }
    }
  }
}

extern "C" void kernel_launch(void* const* d_in, const int* in_sizes, int n_in,
                              void* d_out, int out_size, void* d_ws, size_t ws_size,
                              hipStream_t stream) {
  (void)in_sizes; (void)n_in; (void)out_size;
  const int*   x     = (const int*)d_in[0];
  const float* embed = (const float*)d_in[1];
  const float* w_ih  = (const float*)d_in[2];
  const float* b_ih  = (const float*)d_in[3];
  const float* w_hh  = (const float*)d_in[4];
  const float* b_hh  = (const float*)d_in[5];
  const float* w_out = (const float*)d_in[6];
  const float* b_out = (const float*)d_in[7];
  float* out = (float*)d_out;

  int* flags = (int*)d_ws;                     // 8 KB: prod@0, cons@4KB
  u64* ring  = (u64*)((char*)d_ws + 8192);

  hipLaunchKernelGGL(zero_flags, dim3(2), dim3(1024), 0, stream, flags);

  auto need = [&](int ring_t) { return (size_t)8192 + (size_t)28 * ring_t * 4096; };

  if (ws_size >= need(512)) {        // 57 MB: full history, no back-pressure
    hipLaunchKernelGGL((lstm_pipe<4, 512>), dim3(L_ * NG_), dim3(512), 0, stream,
                       x, embed, w_ih, b_ih, w_hh, b_hh, w_out, b_out, out, flags, ring);
  } else if (ws_size >= need(16)) {  // 1.8 MB
    hipLaunchKernelGGL((lstm_pipe<4, 16>), dim3(L_ * NG_), dim3(512), 0, stream,
                       x, embed, w_ih, b_ih, w_hh, b_hh, w_out, b_out, out, flags, ring);
  } else if (ws_size >= need(8)) {   // 0.92 MB
    hipLaunchKernelGGL((lstm_pipe<4, 8>), dim3(L_ * NG_), dim3(512), 0, stream,
                       x, embed, w_ih, b_ih, w_hh, b_hh, w_out, b_out, out, flags, ring);
  } else {                           // 0.47 MB worst case
    hipLaunchKernelGGL((lstm_pipe<2, 4>), dim3(L_ * NG_), dim3(512), 0, stream,
                       x, embed, w_ih, b_ih, w_hh, b_hh, w_out, b_out, out, flags, ring);
  }
}